// Round 2
// baseline (558.420 us; speedup 1.0000x reference)
//
#include <hip/hip_runtime.h>
#include <hip/hip_bf16.h>
#include <hip/hip_fp16.h>

typedef _Float16 half8 __attribute__((ext_vector_type(8)));
typedef _Float16 half4 __attribute__((ext_vector_type(4)));
typedef float floatx4 __attribute__((ext_vector_type(4)));

#define HID 128
#define TILE_M 32
#define LDA 136   // padded fp16 row stride (272 B)

// ---------------------------------------------------------------------------
// Kernel 1: node_emb[n][c] = x[n]@Wa + ba + pos[n]@Wp + bp   -> fp16
// ---------------------------------------------------------------------------
__global__ __launch_bounds__(256) void node_emb_kernel(
    const float* __restrict__ x, const float* __restrict__ pos,
    const float* __restrict__ Wa, const float* __restrict__ ba,
    const float* __restrict__ Wp, const float* __restrict__ bp,
    _Float16* __restrict__ nodeEmb, int N)
{
    __shared__ float sWa[16 * HID];
    __shared__ float sWp[3 * HID];
    __shared__ float sb[HID];
    for (int i = threadIdx.x; i < 16 * HID; i += 256) sWa[i] = Wa[i];
    for (int i = threadIdx.x; i < 3 * HID;  i += 256) sWp[i] = Wp[i];
    for (int i = threadIdx.x; i < HID;      i += 256) sb[i] = ba[i] + bp[i];
    __syncthreads();

    long long total = (long long)N * HID;
    for (long long idx = (long long)blockIdx.x * 256 + threadIdx.x; idx < total;
         idx += (long long)gridDim.x * 256) {
        int n = (int)(idx >> 7);
        int c = (int)(idx & (HID - 1));
        const float* xr = x + (size_t)n * 16;
        const float* pr = pos + (size_t)n * 3;
        float s = sb[c];
        #pragma unroll
        for (int k = 0; k < 16; ++k) s += xr[k] * sWa[k * HID + c];
        #pragma unroll
        for (int k = 0; k < 3; ++k)  s += pr[k] * sWp[k * HID + c];
        nodeEmb[idx] = (_Float16)s;
    }
}

// ---------------------------------------------------------------------------
// Kernel 2: per-edge MLP, all three layers on MFMA.
// Swapped-operand trick: mfma(W_frag, X_frag) -> D[m=weight_col][n=edge_row],
// so each lane's 4 C-regs are 4 consecutive output columns of ONE edge row
// (vectorized ds_write_b64 epilogues; float4 global store for logits).
// ---------------------------------------------------------------------------
__global__ __launch_bounds__(256, 3) void edge_mlp_kernel(
    const _Float16* __restrict__ nodeEmb,
    const float* __restrict__ pos,
    const int* __restrict__ eidx,          // [2][E]
    const float* __restrict__ W1, const float* __restrict__ b1,   // [257][128]
    const float* __restrict__ W2, const float* __restrict__ b2,   // [128][128]
    const float* __restrict__ W3, const float* __restrict__ b3,   // [128][4]
    float* __restrict__ out, int E, int nTiles)
{
    __shared__ __align__(16) _Float16 sA[2][TILE_M][LDA]; // src/dst gathered rows
    __shared__ __align__(16) _Float16 sH[TILE_M][LDA];    // H1 then H2
    __shared__ float sDist[TILE_M];

    const int t    = threadIdx.x;
    const int wave = t >> 6;
    const int lane = t & 63;
    const int quad = lane >> 4;
    const int l16  = lane & 15;
    const int colbase = wave * 32;        // each wave owns 32 output columns

    // ---- preload weight fragments (layout: frag[j] = W[k0+quad*8+j][col]) ----
    half8 w1f[8][2];
    half8 w2f[4][2];
    half8 w3f[4];
    float w1c[2][4], b1f[2][4], b2f[2][4];
    #pragma unroll
    for (int ct = 0; ct < 2; ++ct) {
        int col = colbase + ct * 16 + l16;
        #pragma unroll
        for (int kc = 0; kc < 8; ++kc)
            #pragma unroll
            for (int j = 0; j < 8; ++j)
                w1f[kc][ct][j] = (_Float16)W1[(kc * 32 + quad * 8 + j) * HID + col];
        #pragma unroll
        for (int kc = 0; kc < 4; ++kc)
            #pragma unroll
            for (int j = 0; j < 8; ++j)
                w2f[kc][ct][j] = (_Float16)W2[(kc * 32 + quad * 8 + j) * HID + col];
        #pragma unroll
        for (int i = 0; i < 4; ++i) {
            int c2 = colbase + ct * 16 + quad * 4 + i;
            w1c[ct][i] = W1[256 * HID + c2];
            b1f[ct][i] = b1[c2];
            b2f[ct][i] = b2[c2];
        }
    }
    #pragma unroll
    for (int kc = 0; kc < 4; ++kc)
        #pragma unroll
        for (int j = 0; j < 8; ++j)
            w3f[kc][j] = (_Float16)W3[(kc * 32 + quad * 8 + j) * 4 + (l16 & 3)];
    const float b3v0 = b3[0], b3v1 = b3[1], b3v2 = b3[2], b3v3 = b3[3];

    for (int tile = blockIdx.x; tile < nTiles; tile += gridDim.x) {
        __syncthreads();  // prev iteration's sA/sH/sDist readers done
        const int ebase = tile * TILE_M;

        // ---- gather src/dst embedding rows (fp16, 16B chunks) ----
        #pragma unroll
        for (int i = 0; i < 4; ++i) {
            int cid  = i * 256 + t;          // 0..1023 chunks of 16B
            int half_ = cid >> 9;            // 0 = src, 1 = dst
            int r    = (cid >> 4) & 31;      // edge row in tile
            int c16  = cid & 15;             // 16B chunk within 256B row
            int e    = ebase + r; if (e >= E) e = E - 1;
            int node = eidx[(size_t)half_ * E + e];
            const uint4* gp = (const uint4*)(nodeEmb + (size_t)node * HID) + c16;
            *(uint4*)(&sA[half_][r][c16 * 8]) = *gp;
        }
        if (t < TILE_M) {
            int e = ebase + t; if (e >= E) e = E - 1;
            int s = eidx[e], d = eidx[(size_t)E + e];
            float dx = pos[3 * (size_t)s]     - pos[3 * (size_t)d];
            float dy = pos[3 * (size_t)s + 1] - pos[3 * (size_t)d + 1];
            float dz = pos[3 * (size_t)s + 2] - pos[3 * (size_t)d + 2];
            sDist[t] = sqrtf(dx * dx + dy * dy + dz * dz);
        }
        __syncthreads();

        // ---- layer 1: accT[ct][rt] = D[col 16-tile ct][edge rows rt] ----
        floatx4 accT[2][2];
        #pragma unroll
        for (int ct = 0; ct < 2; ++ct)
            #pragma unroll
            for (int rt = 0; rt < 2; ++rt)
                accT[ct][rt] = (floatx4){0.f, 0.f, 0.f, 0.f};
        #pragma unroll
        for (int kc = 0; kc < 8; ++kc) {
            int buf = kc >> 2;                    // k<128 -> src, else dst
            int kin = (kc & 3) * 32 + quad * 8;
            half8 a0 = *(const half8*)&sA[buf][l16][kin];
            half8 a1 = *(const half8*)&sA[buf][16 + l16][kin];
            accT[0][0] = __builtin_amdgcn_mfma_f32_16x16x32_f16(w1f[kc][0], a0, accT[0][0], 0, 0, 0);
            accT[0][1] = __builtin_amdgcn_mfma_f32_16x16x32_f16(w1f[kc][0], a1, accT[0][1], 0, 0, 0);
            accT[1][0] = __builtin_amdgcn_mfma_f32_16x16x32_f16(w1f[kc][1], a0, accT[1][0], 0, 0, 0);
            accT[1][1] = __builtin_amdgcn_mfma_f32_16x16x32_f16(w1f[kc][1], a1, accT[1][1], 0, 0, 0);
        }
        // epilogue: lane holds cols [colbase+ct*16+quad*4 .. +3] of edge row rt*16+l16
        #pragma unroll
        for (int ct = 0; ct < 2; ++ct)
            #pragma unroll
            for (int rt = 0; rt < 2; ++rt) {
                int m = rt * 16 + l16;
                float d = sDist[m];
                half4 pk;
                #pragma unroll
                for (int i = 0; i < 4; ++i) {
                    float v = accT[ct][rt][i] + d * w1c[ct][i] + b1f[ct][i];
                    v = v / (1.f + __expf(-v));
                    pk[i] = (_Float16)v;
                }
                *(half4*)&sH[m][colbase + ct * 16 + quad * 4] = pk;
            }
        __syncthreads();

        // ---- layer 2 ----
        floatx4 acc2[2][2];
        #pragma unroll
        for (int ct = 0; ct < 2; ++ct)
            #pragma unroll
            for (int rt = 0; rt < 2; ++rt)
                acc2[ct][rt] = (floatx4){0.f, 0.f, 0.f, 0.f};
        #pragma unroll
        for (int kc = 0; kc < 4; ++kc) {
            int kin = kc * 32 + quad * 8;
            half8 a0 = *(const half8*)&sH[l16][kin];
            half8 a1 = *(const half8*)&sH[16 + l16][kin];
            acc2[0][0] = __builtin_amdgcn_mfma_f32_16x16x32_f16(w2f[kc][0], a0, acc2[0][0], 0, 0, 0);
            acc2[0][1] = __builtin_amdgcn_mfma_f32_16x16x32_f16(w2f[kc][0], a1, acc2[0][1], 0, 0, 0);
            acc2[1][0] = __builtin_amdgcn_mfma_f32_16x16x32_f16(w2f[kc][1], a0, acc2[1][0], 0, 0, 0);
            acc2[1][1] = __builtin_amdgcn_mfma_f32_16x16x32_f16(w2f[kc][1], a1, acc2[1][1], 0, 0, 0);
        }
        __syncthreads();  // all sH (H1) reads done before overwrite
        #pragma unroll
        for (int ct = 0; ct < 2; ++ct)
            #pragma unroll
            for (int rt = 0; rt < 2; ++rt) {
                int m = rt * 16 + l16;
                half4 pk;
                #pragma unroll
                for (int i = 0; i < 4; ++i) {
                    float v = acc2[ct][rt][i] + b2f[ct][i];
                    v = v / (1.f + __expf(-v));
                    pk[i] = (_Float16)v;
                }
                *(half4*)&sH[m][colbase + ct * 16 + quad * 4] = pk;
            }
        __syncthreads();

        // ---- layer 3: waves 0/1, MFMA, quad-0 lanes store float4 logits ----
        if (wave < 2) {
            floatx4 acc3 = (floatx4){0.f, 0.f, 0.f, 0.f};
            #pragma unroll
            for (int kc = 0; kc < 4; ++kc) {
                half8 h = *(const half8*)&sH[wave * 16 + l16][kc * 32 + quad * 8];
                acc3 = __builtin_amdgcn_mfma_f32_16x16x32_f16(w3f[kc], h, acc3, 0, 0, 0);
            }
            if (quad == 0) {
                int e = ebase + wave * 16 + l16;
                if (e < E) {
                    float4 o = {acc3[0] + b3v0, acc3[1] + b3v1,
                                acc3[2] + b3v2, acc3[3] + b3v3};
                    *(float4*)&out[(size_t)e * 4] = o;
                }
            }
        }
    }
}

extern "C" void kernel_launch(void* const* d_in, const int* in_sizes, int n_in,
                              void* d_out, int out_size, void* d_ws, size_t ws_size,
                              hipStream_t stream) {
    const float* x   = (const float*)d_in[0];
    const float* pos = (const float*)d_in[1];
    const int*  eidx = (const int*)d_in[2];
    const float* Wa = (const float*)d_in[3];
    const float* ba = (const float*)d_in[4];
    const float* Wp = (const float*)d_in[5];
    const float* bp = (const float*)d_in[6];
    const float* W1 = (const float*)d_in[7];
    const float* b1 = (const float*)d_in[8];
    const float* W2 = (const float*)d_in[9];
    const float* b2 = (const float*)d_in[10];
    const float* W3 = (const float*)d_in[11];
    const float* b3 = (const float*)d_in[12];
    float* out = (float*)d_out;

    int N = in_sizes[0] / 16;   // ATOM_DIM
    int E = in_sizes[2] / 2;

    _Float16* nodeEmb = (_Float16*)d_ws;   // N*128 fp16 = 25.6 MB

    node_emb_kernel<<<2048, 256, 0, stream>>>(x, pos, Wa, ba, Wp, bp, nodeEmb, N);

    int nTiles = (E + TILE_M - 1) / TILE_M;
    edge_mlp_kernel<<<768, 256, 0, stream>>>(nodeEmb, pos, eidx,
                                             W1, b1, W2, b2, W3, b3,
                                             out, E, nTiles);
}

// Round 3
// 538.826 us; speedup vs baseline: 1.0364x; 1.0364x over previous
//
#include <hip/hip_runtime.h>
#include <hip/hip_bf16.h>
#include <hip/hip_fp16.h>

typedef _Float16 half8 __attribute__((ext_vector_type(8)));
typedef _Float16 half4 __attribute__((ext_vector_type(4)));
typedef float floatx4 __attribute__((ext_vector_type(4)));

#define HID 128
#define TILE_M 64
#define LDA 136   // padded fp16 row stride (272 B)

// ---------------------------------------------------------------------------
// Kernel 1: node_emb[n][c] = x[n]@Wa + ba + pos[n]@Wp + bp   -> fp16
// one thread per (node, 8-col group): x row held in regs, half8 store
// ---------------------------------------------------------------------------
__global__ __launch_bounds__(256) void node_emb_kernel(
    const float* __restrict__ x, const float* __restrict__ pos,
    const float* __restrict__ Wa, const float* __restrict__ ba,
    const float* __restrict__ Wp, const float* __restrict__ bp,
    _Float16* __restrict__ nodeEmb, int N)
{
    __shared__ float sWa[16 * HID];
    __shared__ float sWp[3 * HID];
    __shared__ float sb[HID];
    for (int i = threadIdx.x; i < 16 * HID; i += 256) sWa[i] = Wa[i];
    for (int i = threadIdx.x; i < 3 * HID;  i += 256) sWp[i] = Wp[i];
    for (int i = threadIdx.x; i < HID;      i += 256) sb[i] = ba[i] + bp[i];
    __syncthreads();

    int total = N * 16;
    for (int gid = blockIdx.x * 256 + threadIdx.x; gid < total;
         gid += gridDim.x * 256) {
        int n  = gid >> 4;
        int c0 = (gid & 15) * 8;
        const float* xr = x + (size_t)n * 16;
        const float* pr = pos + (size_t)n * 3;
        float xv[16];
        #pragma unroll
        for (int k = 0; k < 4; ++k) {
            float4 v = *(const float4*)(xr + k * 4);
            xv[k*4] = v.x; xv[k*4+1] = v.y; xv[k*4+2] = v.z; xv[k*4+3] = v.w;
        }
        float p0 = pr[0], p1 = pr[1], p2 = pr[2];
        half8 o;
        #pragma unroll
        for (int i = 0; i < 8; ++i) {
            int c = c0 + i;
            float s = sb[c];
            #pragma unroll
            for (int k = 0; k < 16; ++k) s += xv[k] * sWa[k * HID + c];
            s += p0 * sWp[c] + p1 * sWp[HID + c] + p2 * sWp[2 * HID + c];
            o[i] = (_Float16)s;
        }
        *(half8*)(nodeEmb + (size_t)n * HID + c0) = o;
    }
}

// ---------------------------------------------------------------------------
// Kernel 2: per-edge MLP, 64 edges/tile, register-prefetched gathers,
// 3 barriers/tile (separate H1/H2 LDS buffers), all layers on MFMA.
// ---------------------------------------------------------------------------
__global__ __launch_bounds__(256, 2) void edge_mlp_kernel(
    const _Float16* __restrict__ nodeEmb,
    const float* __restrict__ pos,
    const int* __restrict__ eidx,          // [2][E]
    const float* __restrict__ W1, const float* __restrict__ b1,   // [257][128]
    const float* __restrict__ W2, const float* __restrict__ b2,   // [128][128]
    const float* __restrict__ W3, const float* __restrict__ b3,   // [128][4]
    float* __restrict__ out, int E, int nTiles)
{
    __shared__ __align__(16) _Float16 sA[2][TILE_M][LDA];  // gathered src/dst rows
    __shared__ __align__(16) _Float16 sH1[TILE_M][LDA];    // layer-1 activations
    __shared__ __align__(16) _Float16 sH2[TILE_M][LDA];    // layer-2 activations
    __shared__ float sDist[TILE_M];

    const int t    = threadIdx.x;
    const int wave = t >> 6;
    const int lane = t & 63;
    const int quad = lane >> 4;
    const int l16  = lane & 15;
    const int colbase = wave * 32;        // each wave owns 32 output columns

    // ---- preload weight fragments (frag[j] = W[k0+quad*8+j][col]) ----
    half8 w1f[8][2];
    half8 w2f[4][2];
    half8 w3f[4];
    float w1c[2][4], b1f[2][4], b2f[2][4];
    #pragma unroll
    for (int ct = 0; ct < 2; ++ct) {
        int col = colbase + ct * 16 + l16;
        #pragma unroll
        for (int kc = 0; kc < 8; ++kc)
            #pragma unroll
            for (int j = 0; j < 8; ++j)
                w1f[kc][ct][j] = (_Float16)W1[(kc * 32 + quad * 8 + j) * HID + col];
        #pragma unroll
        for (int kc = 0; kc < 4; ++kc)
            #pragma unroll
            for (int j = 0; j < 8; ++j)
                w2f[kc][ct][j] = (_Float16)W2[(kc * 32 + quad * 8 + j) * HID + col];
        #pragma unroll
        for (int i = 0; i < 4; ++i) {
            int c2 = colbase + ct * 16 + quad * 4 + i;
            w1c[ct][i] = W1[256 * HID + c2];
            b1f[ct][i] = b1[c2];
            b2f[ct][i] = b2[c2];
        }
    }
    #pragma unroll
    for (int kc = 0; kc < 4; ++kc)
        #pragma unroll
        for (int j = 0; j < 8; ++j)
            w3f[kc][j] = (_Float16)W3[(kc * 32 + quad * 8 + j) * 4 + (l16 & 3)];
    const float b3v0 = b3[0], b3v1 = b3[1], b3v2 = b3[2], b3v3 = b3[3];

    // ---- prefetch state: 2 bufs x 64 rows x 16 chunks = 2048 / 256 thr = 8 ----
    uint4 g[8];
    float dpre = 0.f;

    auto issue_gather = [&](int tl) {
        int eb = tl * TILE_M;
        #pragma unroll
        for (int i = 0; i < 8; ++i) {
            int cid  = i * 256 + t;
            int hf   = cid >> 10;
            int r    = (cid >> 4) & 63;
            int c16  = cid & 15;
            int e = eb + r; if (e >= E) e = E - 1;
            int node = eidx[(size_t)hf * E + e];
            g[i] = *((const uint4*)(nodeEmb + (size_t)node * HID) + c16);
        }
        if (t < TILE_M) {
            int e = eb + t; if (e >= E) e = E - 1;
            int s = eidx[e], d = eidx[(size_t)E + e];
            float dx = pos[3 * (size_t)s]     - pos[3 * (size_t)d];
            float dy = pos[3 * (size_t)s + 1] - pos[3 * (size_t)d + 1];
            float dz = pos[3 * (size_t)s + 2] - pos[3 * (size_t)d + 2];
            dpre = sqrtf(dx * dx + dy * dy + dz * dz);
        }
    };

    int tile = blockIdx.x;
    if (tile < nTiles) issue_gather(tile);

    for (; tile < nTiles; tile += gridDim.x) {
        const int ebase = tile * TILE_M;

        // ---- stage prefetched tile into LDS ----
        #pragma unroll
        for (int i = 0; i < 8; ++i) {
            int cid = i * 256 + t;
            int hf  = cid >> 10;
            int r   = (cid >> 4) & 63;
            int c16 = cid & 15;
            *(uint4*)&sA[hf][r][c16 * 8] = g[i];
        }
        if (t < TILE_M) sDist[t] = dpre;
        __syncthreads();                                   // B1

        // ---- issue next tile's gathers (overlap with L1 compute) ----
        int nxt = tile + gridDim.x;
        if (nxt < nTiles) issue_gather(nxt);

        // ---- layer 1: D[col][edge] via mfma(W_frag, X_frag) ----
        floatx4 acc[2][4];
        #pragma unroll
        for (int ct = 0; ct < 2; ++ct)
            #pragma unroll
            for (int rt = 0; rt < 4; ++rt)
                acc[ct][rt] = (floatx4){0.f, 0.f, 0.f, 0.f};
        #pragma unroll
        for (int kc = 0; kc < 8; ++kc) {
            int buf = kc >> 2;                    // k<128 -> src, else dst
            int kin = (kc & 3) * 32 + quad * 8;
            half8 a0 = *(const half8*)&sA[buf][l16][kin];
            half8 a1 = *(const half8*)&sA[buf][16 + l16][kin];
            half8 a2 = *(const half8*)&sA[buf][32 + l16][kin];
            half8 a3 = *(const half8*)&sA[buf][48 + l16][kin];
            acc[0][0] = __builtin_amdgcn_mfma_f32_16x16x32_f16(w1f[kc][0], a0, acc[0][0], 0, 0, 0);
            acc[0][1] = __builtin_amdgcn_mfma_f32_16x16x32_f16(w1f[kc][0], a1, acc[0][1], 0, 0, 0);
            acc[0][2] = __builtin_amdgcn_mfma_f32_16x16x32_f16(w1f[kc][0], a2, acc[0][2], 0, 0, 0);
            acc[0][3] = __builtin_amdgcn_mfma_f32_16x16x32_f16(w1f[kc][0], a3, acc[0][3], 0, 0, 0);
            acc[1][0] = __builtin_amdgcn_mfma_f32_16x16x32_f16(w1f[kc][1], a0, acc[1][0], 0, 0, 0);
            acc[1][1] = __builtin_amdgcn_mfma_f32_16x16x32_f16(w1f[kc][1], a1, acc[1][1], 0, 0, 0);
            acc[1][2] = __builtin_amdgcn_mfma_f32_16x16x32_f16(w1f[kc][1], a2, acc[1][2], 0, 0, 0);
            acc[1][3] = __builtin_amdgcn_mfma_f32_16x16x32_f16(w1f[kc][1], a3, acc[1][3], 0, 0, 0);
        }
        // epilogue: lane = cols [colbase+ct*16+quad*4 ..+3] of edge row rt*16+l16
        #pragma unroll
        for (int ct = 0; ct < 2; ++ct)
            #pragma unroll
            for (int rt = 0; rt < 4; ++rt) {
                int m = rt * 16 + l16;
                float d = sDist[m];
                half4 pk;
                #pragma unroll
                for (int i = 0; i < 4; ++i) {
                    float v = acc[ct][rt][i] + d * w1c[ct][i] + b1f[ct][i];
                    v = v / (1.f + __expf(-v));
                    pk[i] = (_Float16)v;
                }
                *(half4*)&sH1[m][colbase + ct * 16 + quad * 4] = pk;
            }
        __syncthreads();                                   // B2

        // ---- layer 2: reads sH1, writes sH2 (no WAR barrier needed) ----
        floatx4 acc2[2][4];
        #pragma unroll
        for (int ct = 0; ct < 2; ++ct)
            #pragma unroll
            for (int rt = 0; rt < 4; ++rt)
                acc2[ct][rt] = (floatx4){0.f, 0.f, 0.f, 0.f};
        #pragma unroll
        for (int kc = 0; kc < 4; ++kc) {
            int kin = kc * 32 + quad * 8;
            half8 a0 = *(const half8*)&sH1[l16][kin];
            half8 a1 = *(const half8*)&sH1[16 + l16][kin];
            half8 a2 = *(const half8*)&sH1[32 + l16][kin];
            half8 a3 = *(const half8*)&sH1[48 + l16][kin];
            acc2[0][0] = __builtin_amdgcn_mfma_f32_16x16x32_f16(w2f[kc][0], a0, acc2[0][0], 0, 0, 0);
            acc2[0][1] = __builtin_amdgcn_mfma_f32_16x16x32_f16(w2f[kc][0], a1, acc2[0][1], 0, 0, 0);
            acc2[0][2] = __builtin_amdgcn_mfma_f32_16x16x32_f16(w2f[kc][0], a2, acc2[0][2], 0, 0, 0);
            acc2[0][3] = __builtin_amdgcn_mfma_f32_16x16x32_f16(w2f[kc][0], a3, acc2[0][3], 0, 0, 0);
            acc2[1][0] = __builtin_amdgcn_mfma_f32_16x16x32_f16(w2f[kc][1], a0, acc2[1][0], 0, 0, 0);
            acc2[1][1] = __builtin_amdgcn_mfma_f32_16x16x32_f16(w2f[kc][1], a1, acc2[1][1], 0, 0, 0);
            acc2[1][2] = __builtin_amdgcn_mfma_f32_16x16x32_f16(w2f[kc][1], a2, acc2[1][2], 0, 0, 0);
            acc2[1][3] = __builtin_amdgcn_mfma_f32_16x16x32_f16(w2f[kc][1], a3, acc2[1][3], 0, 0, 0);
        }
        #pragma unroll
        for (int ct = 0; ct < 2; ++ct)
            #pragma unroll
            for (int rt = 0; rt < 4; ++rt) {
                int m = rt * 16 + l16;
                half4 pk;
                #pragma unroll
                for (int i = 0; i < 4; ++i) {
                    float v = acc2[ct][rt][i] + b2f[ct][i];
                    v = v / (1.f + __expf(-v));
                    pk[i] = (_Float16)v;
                }
                *(half4*)&sH2[m][colbase + ct * 16 + quad * 4] = pk;
            }
        __syncthreads();                                   // B3

        // ---- layer 3: all 4 waves, wave handles rows wave*16..+15 ----
        {
            floatx4 acc3 = (floatx4){0.f, 0.f, 0.f, 0.f};
            #pragma unroll
            for (int kc = 0; kc < 4; ++kc) {
                half8 h = *(const half8*)&sH2[wave * 16 + l16][kc * 32 + quad * 8];
                acc3 = __builtin_amdgcn_mfma_f32_16x16x32_f16(w3f[kc], h, acc3, 0, 0, 0);
            }
            if (quad == 0) {
                int e = ebase + wave * 16 + l16;
                if (e < E) {
                    float4 o = {acc3[0] + b3v0, acc3[1] + b3v1,
                                acc3[2] + b3v2, acc3[3] + b3v3};
                    *(float4*)&out[(size_t)e * 4] = o;
                }
            }
        }
        // loop top overwrites sA/sDist: last readers (L1/epilogue) were pre-B2,
        // and post-B3 compute touches only sH2/out -> no extra barrier needed.
    }
}

extern "C" void kernel_launch(void* const* d_in, const int* in_sizes, int n_in,
                              void* d_out, int out_size, void* d_ws, size_t ws_size,
                              hipStream_t stream) {
    const float* x   = (const float*)d_in[0];
    const float* pos = (const float*)d_in[1];
    const int*  eidx = (const int*)d_in[2];
    const float* Wa = (const float*)d_in[3];
    const float* ba = (const float*)d_in[4];
    const float* Wp = (const float*)d_in[5];
    const float* bp = (const float*)d_in[6];
    const float* W1 = (const float*)d_in[7];
    const float* b1 = (const float*)d_in[8];
    const float* W2 = (const float*)d_in[9];
    const float* b2 = (const float*)d_in[10];
    const float* W3 = (const float*)d_in[11];
    const float* b3 = (const float*)d_in[12];
    float* out = (float*)d_out;

    int N = in_sizes[0] / 16;   // ATOM_DIM
    int E = in_sizes[2] / 2;

    _Float16* nodeEmb = (_Float16*)d_ws;   // N*128 fp16 = 25.6 MB

    int nodeBlocks = (N * 16 + 255) / 256;
    node_emb_kernel<<<nodeBlocks, 256, 0, stream>>>(x, pos, Wa, ba, Wp, bp, nodeEmb, N);

    int nTiles = (E + TILE_M - 1) / TILE_M;
    edge_mlp_kernel<<<512, 256, 0, stream>>>(nodeEmb, pos, eidx,
                                             W1, b1, W2, b2, W3, b3,
                                             out, E, nTiles);
}

// Round 5
// 348.867 us; speedup vs baseline: 1.6007x; 1.5445x over previous
//
#include <hip/hip_runtime.h>
#include <hip/hip_bf16.h>
#include <hip/hip_fp16.h>

typedef _Float16 half8 __attribute__((ext_vector_type(8)));
typedef __fp16 fp16x2 __attribute__((ext_vector_type(2)));
typedef float floatx4 __attribute__((ext_vector_type(4)));

#define HID 128
#define TILE_M 64
#define LDH 136   // padded fp16 row stride for sH1/sH2 (272 B)

__device__ __forceinline__ float fast_silu(float v) {
    // v * rcp(1+e^-v): v_exp + v_rcp, avoids the IEEE div sequence
    float e = __expf(-v);
    return v * __builtin_amdgcn_rcpf(1.f + e);
}

__device__ __forceinline__ unsigned int pk2(float a, float b) {
    fp16x2 h = __builtin_amdgcn_cvt_pkrtz(a, b);
    return __builtin_bit_cast(unsigned int, h);
}

// ---------------------------------------------------------------------------
// Kernel 1: node_emb[n][c] = x[n]@Wa + ba + pos[n]@Wp + bp   -> fp16
// ---------------------------------------------------------------------------
__global__ __launch_bounds__(256) void node_emb_kernel(
    const float* __restrict__ x, const float* __restrict__ pos,
    const float* __restrict__ Wa, const float* __restrict__ ba,
    const float* __restrict__ Wp, const float* __restrict__ bp,
    _Float16* __restrict__ nodeEmb, int N)
{
    __shared__ float sWa[16 * HID];
    __shared__ float sWp[3 * HID];
    __shared__ float sb[HID];
    for (int i = threadIdx.x; i < 16 * HID; i += 256) sWa[i] = Wa[i];
    for (int i = threadIdx.x; i < 3 * HID;  i += 256) sWp[i] = Wp[i];
    for (int i = threadIdx.x; i < HID;      i += 256) sb[i] = ba[i] + bp[i];
    __syncthreads();

    int total = N * 16;
    for (int gid = blockIdx.x * 256 + threadIdx.x; gid < total;
         gid += gridDim.x * 256) {
        int n  = gid >> 4;
        int c0 = (gid & 15) * 8;
        const float* xr = x + (size_t)n * 16;
        const float* pr = pos + (size_t)n * 3;
        float xv[16];
        #pragma unroll
        for (int k = 0; k < 4; ++k) {
            float4 v = *(const float4*)(xr + k * 4);
            xv[k*4] = v.x; xv[k*4+1] = v.y; xv[k*4+2] = v.z; xv[k*4+3] = v.w;
        }
        float p0 = pr[0], p1 = pr[1], p2 = pr[2];
        half8 o;
        #pragma unroll
        for (int i = 0; i < 8; ++i) {
            int c = c0 + i;
            float s = sb[c];
            #pragma unroll
            for (int k = 0; k < 16; ++k) s += xv[k] * sWa[k * HID + c];
            s += p0 * sWp[c] + p1 * sWp[HID + c] + p2 * sWp[2 * HID + c];
            o[i] = (_Float16)s;
        }
        *(half8*)(nodeEmb + (size_t)n * HID + c0) = o;
    }
}

// ---------------------------------------------------------------------------
// Kernel 2: per-edge MLP. 64 edges/tile, async DMA gathers (global_load_lds),
// XOR-swizzled sA, 2 barriers per tile, layer-3 deferred one tile.
// ---------------------------------------------------------------------------
__global__ __launch_bounds__(256, 2) void edge_mlp_kernel(
    const _Float16* __restrict__ nodeEmb,
    const float* __restrict__ pos,
    const int* __restrict__ eidx,          // [2][E]
    const float* __restrict__ W1, const float* __restrict__ b1,   // [257][128]
    const float* __restrict__ W2, const float* __restrict__ b2,   // [128][128]
    const float* __restrict__ W3, const float* __restrict__ b3,   // [128][4]
    float* __restrict__ out, int E, int nTiles)
{
    // sA: flat [128 rows][128 halves], rows 0-63 = src, 64-127 = dst.
    // 16B chunk c of row r stored at slot (c ^ (r&15)) -> DMA-contiguous AND
    // bank-balanced ds_read_b128.
    __shared__ __align__(16) _Float16 sA[2 * TILE_M * HID];       // 32 KB
    __shared__ __align__(16) _Float16 sH1[TILE_M][LDH];           // 17.4 KB
    __shared__ __align__(16) _Float16 sH2[TILE_M][LDH];           // 17.4 KB
    __shared__ float sDist[TILE_M];

    const int t    = threadIdx.x;
    const int wave = t >> 6;
    const int lane = t & 63;
    const int quad = lane >> 4;
    const int l16  = lane & 15;
    const int colbase = wave * 32;        // each wave owns 32 output columns

    // ---- preload weight fragments (frag[j] = W[k0+quad*8+j][col]) ----
    half8 w1f[8][2];
    half8 w2f[4][2];
    half8 w3f[4];
    float w1c[2][4], b1f[2][4], b2f[2][4];
    #pragma unroll
    for (int ct = 0; ct < 2; ++ct) {
        int col = colbase + ct * 16 + l16;
        #pragma unroll
        for (int kc = 0; kc < 8; ++kc)
            #pragma unroll
            for (int j = 0; j < 8; ++j)
                w1f[kc][ct][j] = (_Float16)W1[(kc * 32 + quad * 8 + j) * HID + col];
        #pragma unroll
        for (int kc = 0; kc < 4; ++kc)
            #pragma unroll
            for (int j = 0; j < 8; ++j)
                w2f[kc][ct][j] = (_Float16)W2[(kc * 32 + quad * 8 + j) * HID + col];
        #pragma unroll
        for (int i = 0; i < 4; ++i) {
            int c2 = colbase + ct * 16 + quad * 4 + i;
            w1c[ct][i] = W1[256 * HID + c2];
            b1f[ct][i] = b1[c2];
            b2f[ct][i] = b2[c2];
        }
    }
    #pragma unroll
    for (int kc = 0; kc < 4; ++kc)
        #pragma unroll
        for (int j = 0; j < 8; ++j)
            w3f[kc][j] = (_Float16)W3[(kc * 32 + quad * 8 + j) * 4 + (l16 & 3)];
    const float b3v0 = b3[0], b3v1 = b3[1], b3v2 = b3[2], b3v3 = b3[3];

    int nid[8];          // next tile's node ids (transient, small)
    float dpre = 0.f;

    auto load_nid = [&](int tl) {
        int eb = tl * TILE_M;
        #pragma unroll
        for (int i = 0; i < 8; ++i) {
            int cid = i * 256 + t;
            int row = cid >> 4;              // 0..127
            int r   = row & 63;
            int e   = eb + r; if (e >= E) e = E - 1;
            nid[i] = (row >> 6) ? eidx[(size_t)E + e] : eidx[e];
        }
    };
    auto load_dist = [&](int tl) -> float {
        if (t >= TILE_M) return 0.f;
        int e = tl * TILE_M + t; if (e >= E) e = E - 1;
        int s = eidx[e], d = eidx[(size_t)E + e];
        float dx = pos[3 * (size_t)s]     - pos[3 * (size_t)d];
        float dy = pos[3 * (size_t)s + 1] - pos[3 * (size_t)d + 1];
        float dz = pos[3 * (size_t)s + 2] - pos[3 * (size_t)d + 2];
        return sqrtf(dx * dx + dy * dy + dz * dz);
    };
    auto dma_issue = [&]() {
        #pragma unroll
        for (int i = 0; i < 8; ++i) {
            int cid = i * 256 + t;
            int row = cid >> 4;
            int cg  = (cid & 15) ^ (row & 15);      // global chunk index
            const _Float16* gp = nodeEmb + (size_t)nid[i] * HID + cg * 8;
            // wave-uniform LDS base; lane's data lands at base + lane*16
            __builtin_amdgcn_global_load_lds(
                (__attribute__((address_space(1))) void*)gp,
                (__attribute__((address_space(3))) void*)&sA[(i * 256 + (t & 192)) * 8],
                16, 0, 0);
        }
    };

    bool havePrev = false;
    int prevEbase = 0;
    int tile = blockIdx.x;
    if (tile < nTiles) {
        load_nid(tile);
        dpre = load_dist(tile);
        dma_issue();                         // -> sA, drains at first B1
    }

    for (; tile < nTiles; tile += gridDim.x) {
        const int ebase = tile * TILE_M;
        if (t < TILE_M) sDist[t] = dpre;
        __syncthreads();                     // B1: sA(T), sDist(T), sH2(T-1) ready

        // ---- layer 3 of previous tile (reads sH2(T-1); no sA/sH1 hazard) ----
        if (havePrev) {
            floatx4 acc3 = (floatx4){0.f, 0.f, 0.f, 0.f};
            #pragma unroll
            for (int kc = 0; kc < 4; ++kc) {
                half8 h = *(const half8*)&sH2[wave * 16 + l16][kc * 32 + quad * 8];
                acc3 = __builtin_amdgcn_mfma_f32_16x16x32_f16(w3f[kc], h, acc3, 0, 0, 0);
            }
            if (quad == 0) {
                int e = prevEbase + wave * 16 + l16;
                if (e < E) {
                    float4 o = {acc3[0] + b3v0, acc3[1] + b3v1,
                                acc3[2] + b3v2, acc3[3] + b3v3};
                    *(float4*)&out[(size_t)e * 4] = o;
                }
            }
        }

        // ---- prefetch next tile metadata (consumed post-B2 / next loop top) ----
        int nxt = tile + gridDim.x;
        if (nxt < nTiles) {
            load_nid(nxt);
            dpre = load_dist(nxt);
        }

        // ---- layer 1: acc init with bias; swizzled sA reads ----
        floatx4 acc[2][4];
        #pragma unroll
        for (int ct = 0; ct < 2; ++ct)
            #pragma unroll
            for (int rt = 0; rt < 4; ++rt) {
                acc[ct][rt][0] = b1f[ct][0]; acc[ct][rt][1] = b1f[ct][1];
                acc[ct][rt][2] = b1f[ct][2]; acc[ct][rt][3] = b1f[ct][3];
            }
        #pragma unroll
        for (int kc = 0; kc < 8; ++kc) {
            int hf   = kc >> 2;                      // src / dst half
            int cg   = (kc & 3) * 4 + quad;          // global chunk
            int slot = (cg ^ l16) * 8;               // swizzled halves offset
            const _Float16* base = &sA[(hf * TILE_M + l16) * HID + slot];
            half8 a0 = *(const half8*)(base + 0 * 16 * HID);
            half8 a1 = *(const half8*)(base + 1 * 16 * HID);
            half8 a2 = *(const half8*)(base + 2 * 16 * HID);
            half8 a3 = *(const half8*)(base + 3 * 16 * HID);
            acc[0][0] = __builtin_amdgcn_mfma_f32_16x16x32_f16(w1f[kc][0], a0, acc[0][0], 0, 0, 0);
            acc[0][1] = __builtin_amdgcn_mfma_f32_16x16x32_f16(w1f[kc][0], a1, acc[0][1], 0, 0, 0);
            acc[0][2] = __builtin_amdgcn_mfma_f32_16x16x32_f16(w1f[kc][0], a2, acc[0][2], 0, 0, 0);
            acc[0][3] = __builtin_amdgcn_mfma_f32_16x16x32_f16(w1f[kc][0], a3, acc[0][3], 0, 0, 0);
            acc[1][0] = __builtin_amdgcn_mfma_f32_16x16x32_f16(w1f[kc][1], a0, acc[1][0], 0, 0, 0);
            acc[1][1] = __builtin_amdgcn_mfma_f32_16x16x32_f16(w1f[kc][1], a1, acc[1][1], 0, 0, 0);
            acc[1][2] = __builtin_amdgcn_mfma_f32_16x16x32_f16(w1f[kc][1], a2, acc[1][2], 0, 0, 0);
            acc[1][3] = __builtin_amdgcn_mfma_f32_16x16x32_f16(w1f[kc][1], a3, acc[1][3], 0, 0, 0);
        }
        // epilogue 1: + dist*w1c, silu, packed cvt, ds_write_b64
        #pragma unroll
        for (int rt = 0; rt < 4; ++rt) {
            int m = rt * 16 + l16;
            float d = sDist[m];
            #pragma unroll
            for (int ct = 0; ct < 2; ++ct) {
                float v0 = fast_silu(fmaf(d, w1c[ct][0], acc[ct][rt][0]));
                float v1 = fast_silu(fmaf(d, w1c[ct][1], acc[ct][rt][1]));
                float v2 = fast_silu(fmaf(d, w1c[ct][2], acc[ct][rt][2]));
                float v3 = fast_silu(fmaf(d, w1c[ct][3], acc[ct][rt][3]));
                uint2 w;
                w.x = pk2(v0, v1);
                w.y = pk2(v2, v3);
                *(uint2*)&sH1[m][colbase + ct * 16 + quad * 4] = w;
            }
        }
        __syncthreads();                     // B2: sH1 visible, sA reads done

        // ---- async DMA for next tile (overlaps L2; drains at next B1) ----
        if (nxt < nTiles) dma_issue();

        // ---- layer 2 ----
        floatx4 acc2[2][4];
        #pragma unroll
        for (int ct = 0; ct < 2; ++ct)
            #pragma unroll
            for (int rt = 0; rt < 4; ++rt) {
                acc2[ct][rt][0] = b2f[ct][0]; acc2[ct][rt][1] = b2f[ct][1];
                acc2[ct][rt][2] = b2f[ct][2]; acc2[ct][rt][3] = b2f[ct][3];
            }
        #pragma unroll
        for (int kc = 0; kc < 4; ++kc) {
            int kin = kc * 32 + quad * 8;
            half8 a0 = *(const half8*)&sH1[l16][kin];
            half8 a1 = *(const half8*)&sH1[16 + l16][kin];
            half8 a2 = *(const half8*)&sH1[32 + l16][kin];
            half8 a3 = *(const half8*)&sH1[48 + l16][kin];
            acc2[0][0] = __builtin_amdgcn_mfma_f32_16x16x32_f16(w2f[kc][0], a0, acc2[0][0], 0, 0, 0);
            acc2[0][1] = __builtin_amdgcn_mfma_f32_16x16x32_f16(w2f[kc][0], a1, acc2[0][1], 0, 0, 0);
            acc2[0][2] = __builtin_amdgcn_mfma_f32_16x16x32_f16(w2f[kc][0], a2, acc2[0][2], 0, 0, 0);
            acc2[0][3] = __builtin_amdgcn_mfma_f32_16x16x32_f16(w2f[kc][0], a3, acc2[0][3], 0, 0, 0);
            acc2[1][0] = __builtin_amdgcn_mfma_f32_16x16x32_f16(w2f[kc][1], a0, acc2[1][0], 0, 0, 0);
            acc2[1][1] = __builtin_amdgcn_mfma_f32_16x16x32_f16(w2f[kc][1], a1, acc2[1][1], 0, 0, 0);
            acc2[1][2] = __builtin_amdgcn_mfma_f32_16x16x32_f16(w2f[kc][1], a2, acc2[1][2], 0, 0, 0);
            acc2[1][3] = __builtin_amdgcn_mfma_f32_16x16x32_f16(w2f[kc][1], a3, acc2[1][3], 0, 0, 0);
        }
        // epilogue 2 -> sH2 (WAR vs L3(T-1) reads: those were pre-B2)
        #pragma unroll
        for (int rt = 0; rt < 4; ++rt) {
            int m = rt * 16 + l16;
            #pragma unroll
            for (int ct = 0; ct < 2; ++ct) {
                float v0 = fast_silu(acc2[ct][rt][0]);
                float v1 = fast_silu(acc2[ct][rt][1]);
                float v2 = fast_silu(acc2[ct][rt][2]);
                float v3 = fast_silu(acc2[ct][rt][3]);
                uint2 w;
                w.x = pk2(v0, v1);
                w.y = pk2(v2, v3);
                *(uint2*)&sH2[m][colbase + ct * 16 + quad * 4] = w;
            }
        }
        havePrev = true;
        prevEbase = ebase;
    }

    // ---- flush: layer 3 of the final tile ----
    if (havePrev) {
        __syncthreads();
        floatx4 acc3 = (floatx4){0.f, 0.f, 0.f, 0.f};
        #pragma unroll
        for (int kc = 0; kc < 4; ++kc) {
            half8 h = *(const half8*)&sH2[wave * 16 + l16][kc * 32 + quad * 8];
            acc3 = __builtin_amdgcn_mfma_f32_16x16x32_f16(w3f[kc], h, acc3, 0, 0, 0);
        }
        if (quad == 0) {
            int e = prevEbase + wave * 16 + l16;
            if (e < E) {
                float4 o = {acc3[0] + b3v0, acc3[1] + b3v1,
                            acc3[2] + b3v2, acc3[3] + b3v3};
                *(float4*)&out[(size_t)e * 4] = o;
            }
        }
    }
}

extern "C" void kernel_launch(void* const* d_in, const int* in_sizes, int n_in,
                              void* d_out, int out_size, void* d_ws, size_t ws_size,
                              hipStream_t stream) {
    const float* x   = (const float*)d_in[0];
    const float* pos = (const float*)d_in[1];
    const int*  eidx = (const int*)d_in[2];
    const float* Wa = (const float*)d_in[3];
    const float* ba = (const float*)d_in[4];
    const float* Wp = (const float*)d_in[5];
    const float* bp = (const float*)d_in[6];
    const float* W1 = (const float*)d_in[7];
    const float* b1 = (const float*)d_in[8];
    const float* W2 = (const float*)d_in[9];
    const float* b2 = (const float*)d_in[10];
    const float* W3 = (const float*)d_in[11];
    const float* b3 = (const float*)d_in[12];
    float* out = (float*)d_out;

    int N = in_sizes[0] / 16;   // ATOM_DIM
    int E = in_sizes[2] / 2;

    _Float16* nodeEmb = (_Float16*)d_ws;   // N*128 fp16 = 25.6 MB

    int nodeBlocks = (N * 16 + 255) / 256;
    node_emb_kernel<<<nodeBlocks, 256, 0, stream>>>(x, pos, Wa, ba, Wp, bp, nodeEmb, N);

    int nTiles = (E + TILE_M - 1) / TILE_M;
    edge_mlp_kernel<<<512, 256, 0, stream>>>(nodeEmb, pos, eidx,
                                             W1, b1, W2, b2, W3, b3,
                                             out, E, nTiles);
}